// Round 2
// baseline (2105.404 us; speedup 1.0000x reference)
//
#include <hip/hip_runtime.h>
#include <hip/hip_bf16.h>

#define Nn 50000
#define Ee 1600000
#define Ff 64
#define Rr 5
#define Bb 4
#define Ll 4
#define Kk 2048

__global__ __launch_bounds__(256) void k_inv_init(int* __restrict__ inv){
  int i = blockIdx.x*256+threadIdx.x;
  if (i < Nn) inv[i] = -1;
}

__global__ __launch_bounds__(256) void k_inv_set(const int* __restrict__ tidx, int* __restrict__ inv){
  int k = blockIdx.x*256+threadIdx.x;
  if (k < Kk) inv[tidx[k]] = k;
}

__global__ __launch_bounds__(256) void k_cnt(const int* __restrict__ ei, const int* __restrict__ et,
                                             int* __restrict__ cnt){
  int e = blockIdx.x*256+threadIdx.x;
  if (e < Ee){
    int dst = ei[Ee + e];
    int r = et[e];
    atomicAdd(&cnt[dst*Rr + r], 1);
  }
}

// Wall: 384x64 fp32. rows 0..319 = W_r (r = row/64, i = row%64), rows 320..383 = root.
__global__ __launch_bounds__(256) void k_wall(const float* __restrict__ bases, const float* __restrict__ comps,
                                              const float* __restrict__ roots, float* __restrict__ Wall){
  int idx = blockIdx.x*256+threadIdx.x;
  if (idx >= 384*64) return;
  int o = idx & 63, row = idx >> 6;
  float s;
  if (row < 320){
    int r = row >> 6, i = row & 63;
    s = 0.f;
    #pragma unroll
    for (int b=0;b<Bb;b++)
      s += comps[r*Bb+b] * bases[(b*Ff + i)*Ff + o];
  } else {
    int i = row - 320;
    s = roots[i*Ff + o];
  }
  Wall[idx] = s;
}

// one edge per 64 lanes; lane f handles feature f. gather h[src] row, scatter-add to xsum[dst,rel].
__global__ __launch_bounds__(256) void k_scatter(const int* __restrict__ ei, const int* __restrict__ et,
                                                 const float* __restrict__ h, float* __restrict__ xsum){
  int idx = blockIdx.x*256+threadIdx.x;
  int e = idx >> 6, f = idx & 63;
  if (e < Ee){
    int src = ei[e];
    int dst = ei[Ee+e];
    int r = et[e];
    float v = h[src*Ff + f];
    unsafeAtomicAdd(&xsum[(dst*Rr + r)*Ff + f], v);
  }
}

// agg[n,o] = sum_{c<5} (xsum[n,c,:]/max(cnt,1)) @ W_c  +  h[n,:] @ root  ; hn = tanh(agg + bias)
// block: 64 nodes x 64 outputs, 256 threads, 16 accumulators/thread (n stride 4, o fixed).
__global__ __launch_bounds__(256) void k_combine(const float* __restrict__ xsum, const int* __restrict__ cnt,
    const float* __restrict__ Wall, const float* __restrict__ h, const float* __restrict__ bias,
    float* __restrict__ hn, const int* __restrict__ inv, float* __restrict__ sel, int layer)
{
  __shared__ float sW[64*64];
  __shared__ float sV[64*64];
  int t = threadIdx.x;
  int n0 = blockIdx.x * 64;
  int o = t & 63;
  int nsub = t >> 6;           // constant per wave -> sV reads are broadcast
  float acc[16];
  #pragma unroll
  for (int j=0;j<16;j++) acc[j]=0.f;

  for (int c=0;c<6;c++){
    for (int idx=t; idx<4096; idx+=256) sW[idx] = Wall[c*4096+idx];
    for (int idx=t; idx<4096; idx+=256){
      int nl = idx>>6, i = idx&63;
      int n = n0 + nl;
      float v = 0.f;
      if (n < Nn){
        if (c < 5){
          int cc = cnt[n*Rr + c];
          v = (cc>0) ? xsum[(n*Rr+c)*Ff + i] / (float)cc : 0.f;
        } else {
          v = h[n*Ff + i];
        }
      }
      sV[idx] = v;
    }
    __syncthreads();
    #pragma unroll 4
    for (int i=0;i<64;i++){
      float w = sW[i*64 + o];
      #pragma unroll
      for (int j=0;j<16;j++) acc[j] += sV[(nsub + (j<<2))*64 + i] * w;
    }
    __syncthreads();
  }

  float bb = bias[o];
  #pragma unroll
  for (int j=0;j<16;j++){
    int n = n0 + nsub + (j<<2);
    if (n < Nn){
      float val = tanhf(acc[j] + bb);
      hn[n*Ff + o] = val;
      int k = inv[n];
      if (k >= 0) sel[(size_t)k*256 + layer*64 + o] = val;
    }
  }
}

__global__ __launch_bounds__(256) void k_w1eff(const float* __restrict__ w1, float* __restrict__ w1e){
  int idx = blockIdx.x*256+threadIdx.x;
  if (idx < 256*128){
    int i = idx >> 7, j = idx & 127;
    w1e[idx] = w1[i*128 + j] + w1[(i+256)*128 + j];
  }
}

__global__ __launch_bounds__(128) void k_mlp(const float* __restrict__ sel, const float* __restrict__ w1e,
    const float* __restrict__ b1, const float* __restrict__ w2, const float* __restrict__ b2,
    float* __restrict__ out)
{
  __shared__ float sfeat[256];
  __shared__ float partial[2];
  int k = blockIdx.x, j = threadIdx.x;   // 128 threads = 2 waves
  for (int idx=j; idx<256; idx+=128) sfeat[idx] = sel[(size_t)k*256 + idx];
  __syncthreads();
  float a = b1[j];
  for (int i=0;i<256;i++) a += sfeat[i] * w1e[i*128 + j];
  a = fmaxf(a, 0.f);
  float v = a * w2[j];
  #pragma unroll
  for (int off=32; off>0; off>>=1) v += __shfl_down(v, off, 64);
  if ((j & 63) == 0) partial[j>>6] = v;
  __syncthreads();
  if (j == 0) out[k] = partial[0] + partial[1] + b2[0];
}

extern "C" void kernel_launch(void* const* d_in, const int* in_sizes, int n_in,
                              void* d_out, int out_size, void* d_ws, size_t ws_size,
                              hipStream_t stream){
  const float* x     = (const float*)d_in[0];
  const int*  ei     = (const int*)d_in[1];   // [2,E] flat: [0..E)=src, [E..2E)=dst
  const int*  et     = (const int*)d_in[2];
  const int*  tidx   = (const int*)d_in[3];
  const float* bases = (const float*)d_in[4]; // [L,B,F,F]
  const float* comps = (const float*)d_in[5]; // [L,R,B]
  const float* roots = (const float*)d_in[6]; // [L,F,F]
  const float* biases= (const float*)d_in[7]; // [L,F]
  const float* w1    = (const float*)d_in[8]; // [512,128]
  const float* b1    = (const float*)d_in[9]; // [128]
  const float* w2    = (const float*)d_in[10];// [128,1]
  const float* b2    = (const float*)d_in[11];// [1]
  float* out = (float*)d_out;

  char* w = (char*)d_ws;
  size_t off = 0;
  auto alloc = [&](size_t bytes)->void*{ void* p = w + off; off += (bytes + 255) & ~size_t(255); return p; };
  float* h0   = (float*)alloc(sizeof(float)*(size_t)Nn*Ff);   // 12.8 MB
  float* h1   = (float*)alloc(sizeof(float)*(size_t)Nn*Ff);   // 12.8 MB
  float* xsum = (float*)alloc(sizeof(float)*(size_t)Nn*Rr*Ff);// 64 MB
  int*   cnt  = (int*)  alloc(sizeof(int)*(size_t)Nn*Rr);     // 1 MB
  float* Wall = (float*)alloc(sizeof(float)*384*64);
  float* sel  = (float*)alloc(sizeof(float)*(size_t)Kk*256);  // 2 MB
  float* w1e  = (float*)alloc(sizeof(float)*256*128);
  int*   inv  = (int*)  alloc(sizeof(int)*(size_t)Nn);
  (void)ws_size;

  hipMemsetAsync(cnt, 0, sizeof(int)*(size_t)Nn*Rr, stream);
  k_inv_init<<<(Nn+255)/256, 256, 0, stream>>>(inv);
  k_inv_set<<<(Kk+255)/256, 256, 0, stream>>>(tidx, inv);
  k_cnt<<<(Ee+255)/256, 256, 0, stream>>>(ei, et, cnt);
  k_w1eff<<<(256*128+255)/256, 256, 0, stream>>>(w1, w1e);

  const float* hc = x;
  float* hn = h0;
  for (int l=0;l<Ll;l++){
    hipMemsetAsync(xsum, 0, sizeof(float)*(size_t)Nn*Rr*Ff, stream);
    k_wall<<<(384*64+255)/256, 256, 0, stream>>>(bases + (size_t)l*Bb*Ff*Ff, comps + (size_t)l*Rr*Bb,
                                                 roots + (size_t)l*Ff*Ff, Wall);
    k_scatter<<<Ee/4, 256, 0, stream>>>(ei, et, hc, xsum);
    k_combine<<<(Nn+63)/64, 256, 0, stream>>>(xsum, cnt, Wall, hc, biases + (size_t)l*Ff, hn, inv, sel, l);
    hc = hn;
    hn = (hn == h0) ? h1 : h0;
  }
  k_mlp<<<Kk, 128, 0, stream>>>(sel, w1e, b1, w2, b2, out);
}